// Round 9
// baseline (1400.543 us; speedup 1.0000x reference)
//
#include <hip/hip_runtime.h>
#include <hip/hip_bf16.h>
#include <stdint.h>

// CrystalGraphEncoder on MI355X — round 9:
//  R8 post-mortem: 8-deep unroll regressed agg (54->60us); mm3 theory wrong.
//  This round: structural consolidation.
//   - agg by BUCKET (64 rows/block): LDS f32 accumulator + ds_add_f32,
//     consumes bucket-grouped ebuf directly -> csr_build, cols, offs deleted.
//   - edge packed to u32 (rl<<26 | c): scatter payload 4MB, 1 shfl/edge.
//   - gr stored bf16 (halves its write+read traffic).
//   - pool fused into last agg epilogue -> pool_kernel deleted.
//   - agg gather unroll reverted to 4-deep.
//  11 dispatches total.
//
// ws: x_bf16 | gr_bf16 | glpk | ebuf_u32 | bcnt | bstart | bcur | wprep | bgs | pool

#define H 64
#define BSHIFT 6
#define BROWS 64
#define NLOG2E -1.4426950408889634f

typedef __attribute__((ext_vector_type(8))) short bf16x8;
typedef __attribute__((ext_vector_type(4))) float f32x4;

__device__ __forceinline__ ushort f2bf(float f) {  // RNE
  uint32_t u = __float_as_uint(f);
  u = (u + 0x7fffu + ((u >> 16) & 1u)) >> 16;
  return (ushort)u;
}
// pack: hi16 = bf16(lin), lo16 = bf16(gc)
__device__ __forceinline__ uint32_t pack_gl(float gc, float lin) {
  uint32_t ug = __float_as_uint(gc);
  ug = (ug + 0x7fffu + ((ug >> 16) & 1u)) >> 16;
  uint32_t ul = __float_as_uint(lin);
  ul = ((ul + 0x7fffu + ((ul >> 16) & 1u)) >> 16) << 16;
  return ul | ug;
}
__device__ __forceinline__ float unpack_gc(uint32_t p) {
  return __uint_as_float(p << 16);
}
__device__ __forceinline__ float unpack_lin(uint32_t p) {
  return __uint_as_float(p & 0xffff0000u);
}
// arg already holds -log2e*(gr+gc): sigmoid = 1/(1+2^arg)
__device__ __forceinline__ float sig_from_neglog2(float arg) {
  return __builtin_amdgcn_rcpf(1.f + exp2f(arg));
}

// ---------- prep: W -> bf16 frag layout; gate mats scaled by -log2e ----------
__global__ __launch_bounds__(256) void prep_kernel(
    const float* __restrict__ Wl, const float* __restrict__ Wg,
    const float* __restrict__ bg, bf16x8* __restrict__ wprep,
    float* __restrict__ bgs) {
  const int t = blockIdx.x * 256 + threadIdx.x;
  if (t < 192) bgs[t] = bg[t] * NLOG2E;  // 3 layers x 64
  if (t >= 4608) return;
  const int l = t / 1536;
  const int rem = t - l * 1536;
  const int mat = rem >> 9;
  const int rem2 = rem & 511;
  const int nt = rem2 >> 7;
  const int ks = (rem2 >> 6) & 1;
  const int lane = rem2 & 63;
  const int kg = lane >> 4, l15 = lane & 15;
  const float* src;
  float s;
  if (mat == 0)      { src = Wl + (size_t)l * 4096;        s = 1.f; }
  else if (mat == 1) { src = Wg + (size_t)l * 8192;        s = NLOG2E; }
  else               { src = Wg + (size_t)l * 8192 + 4096; s = NLOG2E; }
  bf16x8 v;
#pragma unroll
  for (int j = 0; j < 8; j++)
    v[j] = (short)f2bf(src[(size_t)(ks * 32 + kg * 8 + j) * 64 + nt * 16 + l15] * s);
  wprep[t] = v;
}

// ---------- k1: bucket histogram ----------
__global__ __launch_bounds__(256) void bucket_hist_kernel(
    const int* __restrict__ row, int* __restrict__ bcnt, int E, int nbuck) {
  __shared__ int cnt[2048];
  const int tid = threadIdx.x;
  for (int b = tid; b < nbuck; b += 256) cnt[b] = 0;
  __syncthreads();
  for (int e = blockIdx.x * blockDim.x + tid; e < E; e += gridDim.x * blockDim.x)
    atomicAdd(&cnt[row[e] >> BSHIFT], 1);
  __syncthreads();
  for (int b = tid; b < nbuck; b += 256)
    if (cnt[b]) atomicAdd(&bcnt[b], cnt[b]);
}

// ---------- k2: scan bucket counts (1 block, 2 elems/thread; +pool zero) ----------
__global__ __launch_bounds__(1024) void bucket_scan_kernel(
    const int* __restrict__ bcnt, int* __restrict__ bstart,
    int* __restrict__ bcur, float* __restrict__ pool, int nbuck, int E) {
  __shared__ int sh[1024];
  const int tid = threadIdx.x;
  if (tid < 64) pool[tid] = 0.f;
  const int i0 = 2 * tid, i1 = 2 * tid + 1;
  const int v0 = (i0 < nbuck) ? bcnt[i0] : 0;
  const int v1 = (i1 < nbuck) ? bcnt[i1] : 0;
  const int s = v0 + v1;
  sh[tid] = s;
  __syncthreads();
  for (int off = 1; off < 1024; off <<= 1) {
    const int v = (tid >= off) ? sh[tid - off] : 0;
    __syncthreads();
    sh[tid] += v;
    __syncthreads();
  }
  const int ex = sh[tid] - s;
  if (i0 < nbuck) { bstart[i0] = ex;      bcur[i0] = ex; }
  if (i1 < nbuck) { bstart[i1] = ex + v0; bcur[i1] = ex + v0; }
  if (tid == 0) bstart[nbuck] = E;
}

// ---------- k3: bucket scatter; edge packed (rl<<26 | c) ----------
#define SCHUNK 4096
__global__ __launch_bounds__(256) void bucket_scatter_kernel(
    const int* __restrict__ row, const int* __restrict__ col,
    int* __restrict__ bcur, uint32_t* __restrict__ ebuf, int E, int nbuck) {
  __shared__ int cnt[2048], base[2048];
  const int tid = threadIdx.x;
  const int start = blockIdx.x * SCHUNK;
  const int end = min(start + SCHUNK, E);
  for (int b = tid; b < nbuck; b += 256) cnt[b] = 0;
  __syncthreads();
  for (int e = start + tid; e < end; e += 256)
    atomicAdd(&cnt[row[e] >> BSHIFT], 1);
  __syncthreads();
  for (int b = tid; b < nbuck; b += 256) {
    if (cnt[b]) base[b] = atomicAdd(&bcur[b], cnt[b]);
    cnt[b] = 0;
  }
  __syncthreads();
  for (int e = start + tid; e < end; e += 256) {
    const int r = row[e];
    const int b = r >> BSHIFT;
    const int pos = base[b] + atomicAdd(&cnt[b], 1);
    ebuf[pos] = ((uint32_t)(r & (BROWS - 1)) << 26) | (uint32_t)col[e];
  }
}

// ---------- node matmuls via MFMA; gr stored bf16 ----------
template <bool FIRST>
__global__ __launch_bounds__(256) void node_mm3_mfma(
    const ushort* __restrict__ x, const int* __restrict__ an,
    const float* __restrict__ emb, const bf16x8* __restrict__ wp,
    const float* __restrict__ bl, const float* __restrict__ bgs,
    ushort* __restrict__ gr, uint32_t* __restrict__ glpk, int N) {
  const int tid = threadIdx.x;
  const int lane = tid & 63, wid = tid >> 6;
  const int l15 = lane & 15, kg = lane >> 4;

  bf16x8 bfrag[3][4][2];
#pragma unroll
  for (int mat = 0; mat < 3; mat++)
#pragma unroll
    for (int nt = 0; nt < 4; nt++)
#pragma unroll
      for (int ks = 0; ks < 2; ks++)
        bfrag[mat][nt][ks] = wp[(((mat * 4 + nt) * 2 + ks) << 6) + lane];

  const int mbase = blockIdx.x * 64 + wid * 16;
  const int arow = mbase + l15;
  const int arow_c = min(arow, N - 1);

  bf16x8 afrag0, afrag1;
  if (FIRST) {
    const int a = an[arow_c];
    const float* src = emb + (size_t)a * H + kg * 8;
    const float4 u0 = *(const float4*)(src);
    const float4 u1 = *(const float4*)(src + 4);
    const float4 u2 = *(const float4*)(src + 32);
    const float4 u3 = *(const float4*)(src + 36);
    bf16x8 t0, t1;
    t0[0] = (short)f2bf(u0.x); t0[1] = (short)f2bf(u0.y);
    t0[2] = (short)f2bf(u0.z); t0[3] = (short)f2bf(u0.w);
    t0[4] = (short)f2bf(u1.x); t0[5] = (short)f2bf(u1.y);
    t0[6] = (short)f2bf(u1.z); t0[7] = (short)f2bf(u1.w);
    t1[0] = (short)f2bf(u2.x); t1[1] = (short)f2bf(u2.y);
    t1[2] = (short)f2bf(u2.z); t1[3] = (short)f2bf(u2.w);
    t1[4] = (short)f2bf(u3.x); t1[5] = (short)f2bf(u3.y);
    t1[6] = (short)f2bf(u3.z); t1[7] = (short)f2bf(u3.w);
    afrag0 = t0; afrag1 = t1;
  } else {
    const ushort* src = x + (size_t)arow_c * H + kg * 8;
    afrag0 = *(const bf16x8*)(src);
    afrag1 = *(const bf16x8*)(src + 32);
  }

  f32x4 accL[4], accR[4], accC[4];
#pragma unroll
  for (int nt = 0; nt < 4; nt++) {
    const float blv = bl[nt * 16 + l15];
    const float bgv = bgs[nt * 16 + l15];
    accL[nt] = (f32x4){blv, blv, blv, blv};
    accR[nt] = (f32x4){0.f, 0.f, 0.f, 0.f};
    accC[nt] = (f32x4){bgv, bgv, bgv, bgv};
  }
#pragma unroll
  for (int nt = 0; nt < 4; nt++) {
    accL[nt] = __builtin_amdgcn_mfma_f32_16x16x32_bf16(afrag0, bfrag[0][nt][0], accL[nt], 0, 0, 0);
    accL[nt] = __builtin_amdgcn_mfma_f32_16x16x32_bf16(afrag1, bfrag[0][nt][1], accL[nt], 0, 0, 0);
    accR[nt] = __builtin_amdgcn_mfma_f32_16x16x32_bf16(afrag0, bfrag[1][nt][0], accR[nt], 0, 0, 0);
    accR[nt] = __builtin_amdgcn_mfma_f32_16x16x32_bf16(afrag1, bfrag[1][nt][1], accR[nt], 0, 0, 0);
    accC[nt] = __builtin_amdgcn_mfma_f32_16x16x32_bf16(afrag0, bfrag[2][nt][0], accC[nt], 0, 0, 0);
    accC[nt] = __builtin_amdgcn_mfma_f32_16x16x32_bf16(afrag1, bfrag[2][nt][1], accC[nt], 0, 0, 0);
  }
#pragma unroll
  for (int nt = 0; nt < 4; nt++) {
#pragma unroll
    for (int r = 0; r < 4; r++) {
      const int atom = mbase + kg * 4 + r;
      if (atom < N) {
        const size_t o = (size_t)atom * H + nt * 16 + l15;
        gr[o] = f2bf(accR[nt][r]);
        glpk[o] = pack_gl(accC[nt][r], accL[nt][r]);
      }
    }
  }
}

// ---------- aggregate by bucket: LDS accumulator, lane = channel ----------
// block = bucket of 64 rows; acc[r][ch] += lin_c * sigmoid-from-exp2;
// epilogue: x = bf16(relu(acc + lin_self)); LAST: pool partial per block.
template <bool LAST>
__global__ __launch_bounds__(256) void agg_bucket_kernel(
    const ushort* __restrict__ gr, const uint32_t* __restrict__ glpk,
    const uint32_t* __restrict__ ebuf, const int* __restrict__ bstart,
    ushort* __restrict__ x, float* __restrict__ pool, int N) {
  __shared__ float acc[BROWS * H];    // 16 KB
  __shared__ ushort grs[BROWS * H];   // 8 KB
  __shared__ float pacc[H];
  const int tid = threadIdx.x;
  const int lane = tid & 63, w = tid >> 6;
  const int b = blockIdx.x;
  const int rowbase = b << BSHIFT;

  // stage gr rows (bf16, 8KB) + zero acc (+ pacc)
  {
    const uint4* gsrc = (const uint4*)(gr + (size_t)rowbase * H);
    uint4* gdst = (uint4*)grs;
    gdst[tid] = gsrc[tid];
    gdst[tid + 256] = gsrc[tid + 256];
    float4* az = (float4*)acc;
#pragma unroll
    for (int q = 0; q < 4; q++) az[tid + q * 256] = make_float4(0.f, 0.f, 0.f, 0.f);
    if (LAST && tid < 64) pacc[tid] = 0.f;
  }
  __syncthreads();

  const int bs = bstart[b], be = bstart[b + 1];
  for (int cb = bs + w * 64; cb < be; cb += 256) {
    const int nchunk = min(64, be - cb);
    const uint32_t mye = (lane < nchunk) ? ebuf[cb + lane] : 0;
    int j = 0;
    for (; j + 3 < nchunk; j += 4) {
      const uint32_t e0 = __shfl(mye, j + 0), e1 = __shfl(mye, j + 1);
      const uint32_t e2 = __shfl(mye, j + 2), e3 = __shfl(mye, j + 3);
      const uint32_t p0 = glpk[((e0 & 0x3FFFFFFu) << 6) | lane];
      const uint32_t p1 = glpk[((e1 & 0x3FFFFFFu) << 6) | lane];
      const uint32_t p2 = glpk[((e2 & 0x3FFFFFFu) << 6) | lane];
      const uint32_t p3 = glpk[((e3 & 0x3FFFFFFu) << 6) | lane];
#pragma unroll
      for (int q = 0; q < 4; q++) {
        const uint32_t e = (q == 0) ? e0 : (q == 1) ? e1 : (q == 2) ? e2 : e3;
        const uint32_t p = (q == 0) ? p0 : (q == 1) ? p1 : (q == 2) ? p2 : p3;
        const int rl = (int)(e >> 26);
        const float g = __uint_as_float((uint32_t)grs[(rl << 6) | lane] << 16);
        const float m = unpack_lin(p) * sig_from_neglog2(g + unpack_gc(p));
        atomicAdd(&acc[(rl << 6) | lane], m);
      }
    }
    for (; j < nchunk; j++) {
      const uint32_t e = __shfl(mye, j);
      const uint32_t p = glpk[((e & 0x3FFFFFFu) << 6) | lane];
      const int rl = (int)(e >> 26);
      const float g = __uint_as_float((uint32_t)grs[(rl << 6) | lane] << 16);
      const float m = unpack_lin(p) * sig_from_neglog2(g + unpack_gc(p));
      atomicAdd(&acc[(rl << 6) | lane], m);
    }
  }
  __syncthreads();

  // epilogue: wave w handles rows w*16..w*16+15, lane = channel
  float psum = 0.f;
#pragma unroll
  for (int k = 0; k < 16; k++) {
    const int r = w * 16 + k;
    const int atom = rowbase + r;
    if (atom < N) {
      const float li = unpack_lin(glpk[((size_t)atom << 6) | lane]);
      float v = acc[(r << 6) | lane] + li;
      v = fmaxf(v, 0.f);
      x[((size_t)atom << 6) | lane] = f2bf(v);
      if (LAST) psum += v;
    }
  }
  if (LAST) {
    atomicAdd(&pacc[lane], psum);  // 4 waves, conflict-free per inst
    __syncthreads();
    if (tid < 64) atomicAdd(&pool[tid], pacc[tid]);
  }
}

// ---------- final MLP ----------
__global__ void mlp_kernel(const float* __restrict__ pool,
                           const float* __restrict__ W1,
                           const float* __restrict__ b1,
                           const float* __restrict__ W2,
                           const float* __restrict__ b2,
                           float* __restrict__ out, float invN) {
  __shared__ float p[64], h[64];
  const int tid = threadIdx.x;
  if (tid < 64) p[tid] = pool[tid] * invN;
  __syncthreads();
  if (tid < 64) {
    float s = b1[tid];
    for (int k = 0; k < 64; k++) s = fmaf(p[k], W1[k * 64 + tid], s);
    h[tid] = fmaxf(s, 0.f);
  }
  __syncthreads();
  float s = b2[tid];
  for (int k = 0; k < 64; k++) s = fmaf(h[k], W2[k * 128 + tid], s);
  out[tid] = s;
}

extern "C" void kernel_launch(void* const* d_in, const int* in_sizes, int n_in,
                              void* d_out, int out_size, void* d_ws,
                              size_t ws_size, hipStream_t stream) {
  const int*   an  = (const int*)d_in[0];
  const int*   ei  = (const int*)d_in[3];
  const float* emb = (const float*)d_in[4];
  const float* Wl  = (const float*)d_in[5];
  const float* bl  = (const float*)d_in[6];
  const float* Wg  = (const float*)d_in[7];
  const float* bg  = (const float*)d_in[8];
  const float* W1  = (const float*)d_in[9];
  const float* b1  = (const float*)d_in[10];
  const float* W2  = (const float*)d_in[11];
  const float* b2  = (const float*)d_in[12];
  float* out = (float*)d_out;

  const int N = in_sizes[0];
  const int E = in_sizes[3] / 2;
  const int* row = ei;
  const int* col = ei + E;
  const int nbuck = (N + BROWS - 1) >> BSHIFT;  // 1563 for N=100K (<=2048)

  const size_t NH = (size_t)N * H;
  char* ws = (char*)d_ws;
  ushort*   x    = (ushort*)(ws);                  // bf16 [N][64]
  ushort*   gr   = (ushort*)(ws + NH * 2);         // bf16 [N][64]
  uint32_t* glpk = (uint32_t*)(ws + NH * 4);       // u32  [N][64]
  char* p = ws + NH * 4 + NH * 4;
  uint32_t* ebuf   = (uint32_t*)p; p += (size_t)E * 4;
  int*      bcnt   = (int*)p;      p += 8192;
  int*      bstart = (int*)p;      p += 8196;
  int*      bcur   = (int*)p;      p += 8192;
  bf16x8*   wprep  = (bf16x8*)p;   p += 4608 * 16;
  float*    bgs    = (float*)p;    p += 192 * 4;
  float*    pool   = (float*)p;
  // total ≈ 12.8 + 12.8 + 25.6 + 4 MB + ~120KB ≈ 55 MB

  prep_kernel<<<18, 256, 0, stream>>>(Wl, Wg, bg, wprep, bgs);

  // --- bucket build (edges identical every layer) ---
  hipMemsetAsync(bcnt, 0, (size_t)nbuck * 4, stream);
  bucket_hist_kernel<<<1024, 256, 0, stream>>>(row, bcnt, E, nbuck);
  bucket_scan_kernel<<<1, 1024, 0, stream>>>(bcnt, bstart, bcur, pool, nbuck, E);
  bucket_scatter_kernel<<<(E + SCHUNK - 1) / SCHUNK, 256, 0, stream>>>(
      row, col, bcur, ebuf, E, nbuck);

  const int mmGrid = (N + 63) / 64;
  for (int l = 0; l < 3; l++) {
    const bf16x8* wp  = wprep + (size_t)l * 1536;
    const float*  bll = bl + (size_t)l * H;
    const float*  bgl = bgs + (size_t)l * H;
    if (l == 0)
      node_mm3_mfma<true><<<mmGrid, 256, 0, stream>>>(x, an, emb, wp, bll, bgl,
                                                      gr, glpk, N);
    else
      node_mm3_mfma<false><<<mmGrid, 256, 0, stream>>>(x, an, emb, wp, bll, bgl,
                                                       gr, glpk, N);
    if (l == 2)
      agg_bucket_kernel<true><<<nbuck, 256, 0, stream>>>(gr, glpk, ebuf, bstart,
                                                         x, pool, N);
    else
      agg_bucket_kernel<false><<<nbuck, 256, 0, stream>>>(gr, glpk, ebuf, bstart,
                                                          x, pool, N);
  }

  mlp_kernel<<<1, 128, 0, stream>>>(pool, W1, b1, W2, b2, out, 1.0f / (float)N);
}

// Round 10
// 439.949 us; speedup vs baseline: 3.1834x; 3.1834x over previous
//
#include <hip/hip_runtime.h>
#include <hip/hip_bf16.h>
#include <stdint.h>

// CrystalGraphEncoder on MI355X — round 10:
//  R9 post-mortem: bucket-agg with per-edge LDS atomics = 7x regression
//  (VALU 9%, latency-stalled). Revert to R7's register-accumulate agg
//  (wave=atom, 4-deep), and FUSE next layer's MFMA matmul into the agg
//  epilogue (block = 16 atoms = one 16x64 A-tile):
//   - deletes 2 mm3 dispatches + global x array (~75MB traffic) + pool kernel
//   - gr/glpk double-buffered (A/B) across layers to avoid RAW races
//   - packed u32 ebuf (rl<<26|col) + per-bucket csr_build (64 rows)
//  11 dispatches total.
//
// ws: grA | grB (bf16) | glpkA | glpkB | ebuf | cols | offs | bcnt/bstart/bcur
//     | wprep | bgs | pool  (~85 MB)

#define H 64
#define BSHIFT 6
#define BROWS 64
#define NLOG2E -1.4426950408889634f

typedef __attribute__((ext_vector_type(8))) short bf16x8;
typedef __attribute__((ext_vector_type(4))) float f32x4;

__device__ __forceinline__ ushort f2bf(float f) {  // RNE
  uint32_t u = __float_as_uint(f);
  u = (u + 0x7fffu + ((u >> 16) & 1u)) >> 16;
  return (ushort)u;
}
// pack: hi16 = bf16(lin), lo16 = bf16(gc)
__device__ __forceinline__ uint32_t pack_gl(float gc, float lin) {
  uint32_t ug = __float_as_uint(gc);
  ug = (ug + 0x7fffu + ((ug >> 16) & 1u)) >> 16;
  uint32_t ul = __float_as_uint(lin);
  ul = ((ul + 0x7fffu + ((ul >> 16) & 1u)) >> 16) << 16;
  return ul | ug;
}
__device__ __forceinline__ float unpack_gc(uint32_t p) {
  return __uint_as_float(p << 16);
}
__device__ __forceinline__ float unpack_lin(uint32_t p) {
  return __uint_as_float(p & 0xffff0000u);
}
// arg holds -log2e*(gr+gc): sigmoid = 1/(1+2^arg)
__device__ __forceinline__ float sig_from_neglog2(float arg) {
  return __builtin_amdgcn_rcpf(1.f + exp2f(arg));
}

// ---------- prep: W -> bf16 frag layout; gate mats scaled by -log2e ----------
__global__ __launch_bounds__(256) void prep_kernel(
    const float* __restrict__ Wl, const float* __restrict__ Wg,
    const float* __restrict__ bg, bf16x8* __restrict__ wprep,
    float* __restrict__ bgs) {
  const int t = blockIdx.x * 256 + threadIdx.x;
  if (t < 192) bgs[t] = bg[t] * NLOG2E;
  if (t >= 4608) return;
  const int l = t / 1536;
  const int rem = t - l * 1536;
  const int mat = rem >> 9;
  const int rem2 = rem & 511;
  const int nt = rem2 >> 7;
  const int ks = (rem2 >> 6) & 1;
  const int lane = rem2 & 63;
  const int kg = lane >> 4, l15 = lane & 15;
  const float* src;
  float s;
  if (mat == 0)      { src = Wl + (size_t)l * 4096;        s = 1.f; }
  else if (mat == 1) { src = Wg + (size_t)l * 8192;        s = NLOG2E; }
  else               { src = Wg + (size_t)l * 8192 + 4096; s = NLOG2E; }
  bf16x8 v;
#pragma unroll
  for (int j = 0; j < 8; j++)
    v[j] = (short)f2bf(src[(size_t)(ks * 32 + kg * 8 + j) * 64 + nt * 16 + l15] * s);
  wprep[t] = v;
}

// ---------- k1: bucket histogram ----------
__global__ __launch_bounds__(256) void bucket_hist_kernel(
    const int* __restrict__ row, int* __restrict__ bcnt, int E, int nbuck) {
  __shared__ int cnt[2048];
  const int tid = threadIdx.x;
  for (int b = tid; b < nbuck; b += 256) cnt[b] = 0;
  __syncthreads();
  for (int e = blockIdx.x * blockDim.x + tid; e < E; e += gridDim.x * blockDim.x)
    atomicAdd(&cnt[row[e] >> BSHIFT], 1);
  __syncthreads();
  for (int b = tid; b < nbuck; b += 256)
    if (cnt[b]) atomicAdd(&bcnt[b], cnt[b]);
}

// ---------- k2: scan bucket counts (+pool zero, offs[N]=E) ----------
__global__ __launch_bounds__(1024) void bucket_scan_kernel(
    const int* __restrict__ bcnt, int* __restrict__ bstart,
    int* __restrict__ bcur, int* __restrict__ offs, float* __restrict__ pool,
    int nbuck, int N, int E) {
  __shared__ int sh[1024];
  const int tid = threadIdx.x;
  if (tid < 64) pool[tid] = 0.f;
  const int i0 = 2 * tid, i1 = 2 * tid + 1;
  const int v0 = (i0 < nbuck) ? bcnt[i0] : 0;
  const int v1 = (i1 < nbuck) ? bcnt[i1] : 0;
  const int s = v0 + v1;
  sh[tid] = s;
  __syncthreads();
  for (int off = 1; off < 1024; off <<= 1) {
    const int v = (tid >= off) ? sh[tid - off] : 0;
    __syncthreads();
    sh[tid] += v;
    __syncthreads();
  }
  const int ex = sh[tid] - s;
  if (i0 < nbuck) { bstart[i0] = ex;      bcur[i0] = ex; }
  if (i1 < nbuck) { bstart[i1] = ex + v0; bcur[i1] = ex + v0; }
  if (tid == 0) { bstart[nbuck] = E; offs[N] = E; }
}

// ---------- k3: bucket scatter; edge packed (rl<<26 | c) ----------
#define SCHUNK 4096
__global__ __launch_bounds__(256) void bucket_scatter_kernel(
    const int* __restrict__ row, const int* __restrict__ col,
    int* __restrict__ bcur, uint32_t* __restrict__ ebuf, int E, int nbuck) {
  __shared__ int cnt[2048], base[2048];
  const int tid = threadIdx.x;
  const int start = blockIdx.x * SCHUNK;
  const int end = min(start + SCHUNK, E);
  for (int b = tid; b < nbuck; b += 256) cnt[b] = 0;
  __syncthreads();
  for (int e = start + tid; e < end; e += 256)
    atomicAdd(&cnt[row[e] >> BSHIFT], 1);
  __syncthreads();
  for (int b = tid; b < nbuck; b += 256) {
    if (cnt[b]) base[b] = atomicAdd(&bcur[b], cnt[b]);
    cnt[b] = 0;
  }
  __syncthreads();
  for (int e = start + tid; e < end; e += 256) {
    const int r = row[e];
    const int b = r >> BSHIFT;
    const int pos = base[b] + atomicAdd(&cnt[b], 1);
    ebuf[pos] = ((uint32_t)(r & (BROWS - 1)) << 26) | (uint32_t)col[e];
  }
}

// ---------- k4: per-bucket exact CSR from packed ebuf ----------
__global__ __launch_bounds__(256) void csr_build_kernel(
    const uint32_t* __restrict__ ebuf, const int* __restrict__ bstart,
    int* __restrict__ offs, int* __restrict__ cols, int N) {
  __shared__ int cnt[BROWS], sc[BROWS];
  const int tid = threadIdx.x;
  const int b = blockIdx.x;
  const int bs = bstart[b], be = bstart[b + 1];
  const int rowbase = b << BSHIFT;
  if (tid < BROWS) cnt[tid] = 0;
  __syncthreads();
  for (int e = bs + tid; e < be; e += 256)
    atomicAdd(&cnt[ebuf[e] >> 26], 1);
  __syncthreads();
  if (tid < BROWS) sc[tid] = cnt[tid];
  __syncthreads();
  for (int off = 1; off < BROWS; off <<= 1) {
    const int v = (tid >= off && tid < BROWS) ? sc[tid - off] : 0;
    __syncthreads();
    if (tid < BROWS) sc[tid] += v;
    __syncthreads();
  }
  if (tid < BROWS) {
    sc[tid] -= cnt[tid];
    cnt[tid] = 0;
    const int r = rowbase + tid;
    if (r < N) offs[r] = bs + sc[tid];
  }
  __syncthreads();
  for (int e = bs + tid; e < be; e += 256) {
    const uint32_t u = ebuf[e];
    const int rl = (int)(u >> 26);
    const int pos = sc[rl] + atomicAdd(&cnt[rl], 1);
    cols[bs + pos] = (int)(u & 0x3FFFFFFu);
  }
}

// ---------- mm0: embed -> layer-0 gr/glpk via MFMA ----------
__global__ __launch_bounds__(256) void node_mm0_mfma(
    const int* __restrict__ an, const float* __restrict__ emb,
    const bf16x8* __restrict__ wp, const float* __restrict__ bl,
    const float* __restrict__ bgs, ushort* __restrict__ gr,
    uint32_t* __restrict__ glpk, int N) {
  const int tid = threadIdx.x;
  const int lane = tid & 63, wid = tid >> 6;
  const int l15 = lane & 15, kg = lane >> 4;

  bf16x8 bfrag[3][4][2];
#pragma unroll
  for (int mat = 0; mat < 3; mat++)
#pragma unroll
    for (int nt = 0; nt < 4; nt++)
#pragma unroll
      for (int ks = 0; ks < 2; ks++)
        bfrag[mat][nt][ks] = wp[(((mat * 4 + nt) * 2 + ks) << 6) + lane];

  const int mbase = blockIdx.x * 64 + wid * 16;
  const int arow_c = min(mbase + l15, N - 1);

  const int a = an[arow_c];
  const float* src = emb + (size_t)a * H + kg * 8;
  const float4 u0 = *(const float4*)(src);
  const float4 u1 = *(const float4*)(src + 4);
  const float4 u2 = *(const float4*)(src + 32);
  const float4 u3 = *(const float4*)(src + 36);
  bf16x8 afrag0, afrag1;
  afrag0[0] = (short)f2bf(u0.x); afrag0[1] = (short)f2bf(u0.y);
  afrag0[2] = (short)f2bf(u0.z); afrag0[3] = (short)f2bf(u0.w);
  afrag0[4] = (short)f2bf(u1.x); afrag0[5] = (short)f2bf(u1.y);
  afrag0[6] = (short)f2bf(u1.z); afrag0[7] = (short)f2bf(u1.w);
  afrag1[0] = (short)f2bf(u2.x); afrag1[1] = (short)f2bf(u2.y);
  afrag1[2] = (short)f2bf(u2.z); afrag1[3] = (short)f2bf(u2.w);
  afrag1[4] = (short)f2bf(u3.x); afrag1[5] = (short)f2bf(u3.y);
  afrag1[6] = (short)f2bf(u3.z); afrag1[7] = (short)f2bf(u3.w);

  f32x4 accL[4], accR[4], accC[4];
#pragma unroll
  for (int nt = 0; nt < 4; nt++) {
    const float blv = bl[nt * 16 + l15];
    const float bgv = bgs[nt * 16 + l15];
    accL[nt] = (f32x4){blv, blv, blv, blv};
    accR[nt] = (f32x4){0.f, 0.f, 0.f, 0.f};
    accC[nt] = (f32x4){bgv, bgv, bgv, bgv};
  }
#pragma unroll
  for (int nt = 0; nt < 4; nt++) {
    accL[nt] = __builtin_amdgcn_mfma_f32_16x16x32_bf16(afrag0, bfrag[0][nt][0], accL[nt], 0, 0, 0);
    accL[nt] = __builtin_amdgcn_mfma_f32_16x16x32_bf16(afrag1, bfrag[0][nt][1], accL[nt], 0, 0, 0);
    accR[nt] = __builtin_amdgcn_mfma_f32_16x16x32_bf16(afrag0, bfrag[1][nt][0], accR[nt], 0, 0, 0);
    accR[nt] = __builtin_amdgcn_mfma_f32_16x16x32_bf16(afrag1, bfrag[1][nt][1], accR[nt], 0, 0, 0);
    accC[nt] = __builtin_amdgcn_mfma_f32_16x16x32_bf16(afrag0, bfrag[2][nt][0], accC[nt], 0, 0, 0);
    accC[nt] = __builtin_amdgcn_mfma_f32_16x16x32_bf16(afrag1, bfrag[2][nt][1], accC[nt], 0, 0, 0);
  }
#pragma unroll
  for (int nt = 0; nt < 4; nt++) {
#pragma unroll
    for (int r = 0; r < 4; r++) {
      const int atom = mbase + kg * 4 + r;
      if (atom < N) {
        const size_t o = (size_t)atom * H + nt * 16 + l15;
        gr[o] = f2bf(accR[nt][r]);
        glpk[o] = pack_gl(accC[nt][r], accL[nt][r]);
      }
    }
  }
}

// ---------- fused agg(l) + mm(l+1): block = 16 atoms, 4 waves ----------
// agg: wave w owns atoms base+w*4..+3, R7-style register accumulate.
// mm:  x-tile through LDS; wave w computes output cols nt=w for all 3 mats.
template <bool LAST>
__global__ __launch_bounds__(256) void agg_mm_kernel(
    const ushort* __restrict__ gr, const uint32_t* __restrict__ glpk,
    const int* __restrict__ offs, const int* __restrict__ cols,
    const bf16x8* __restrict__ wp, const float* __restrict__ bl,
    const float* __restrict__ bgs, ushort* __restrict__ gr_out,
    uint32_t* __restrict__ glpk_out, float* __restrict__ pool, int N) {
  __shared__ __align__(16) ushort xs[16][72];  // bf16 x-tile, 144B rows
  __shared__ float pacc[4][64];
  const int tid = threadIdx.x;
  const int lane = tid & 63, w = tid >> 6;
  const int base = blockIdx.x * 16;

  float psum = 0.f;
#pragma unroll 1
  for (int k = 0; k < 4; k++) {
    const int i = base + w * 4 + k;
    float v = 0.f;
    if (i < N) {
      const int s = offs[i], e = offs[i + 1];
      const float gri =
          __uint_as_float((uint32_t)gr[((size_t)i << 6) | lane] << 16);
      float acc = 0.f;
      for (int cb = s; cb < e; cb += 64) {
        const int nchunk = min(64, e - cb);
        const int myc = (lane < nchunk) ? cols[cb + lane] : 0;
        int j = 0;
        for (; j + 3 < nchunk; j += 4) {
          const int c0 = __shfl(myc, j + 0), c1 = __shfl(myc, j + 1);
          const int c2 = __shfl(myc, j + 2), c3 = __shfl(myc, j + 3);
          const uint32_t p0 = glpk[((size_t)c0 << 6) | lane];
          const uint32_t p1 = glpk[((size_t)c1 << 6) | lane];
          const uint32_t p2 = glpk[((size_t)c2 << 6) | lane];
          const uint32_t p3 = glpk[((size_t)c3 << 6) | lane];
          acc += unpack_lin(p0) * sig_from_neglog2(gri + unpack_gc(p0));
          acc += unpack_lin(p1) * sig_from_neglog2(gri + unpack_gc(p1));
          acc += unpack_lin(p2) * sig_from_neglog2(gri + unpack_gc(p2));
          acc += unpack_lin(p3) * sig_from_neglog2(gri + unpack_gc(p3));
        }
        for (; j < nchunk; j++) {
          const int c0 = __shfl(myc, j);
          const uint32_t p0 = glpk[((size_t)c0 << 6) | lane];
          acc += unpack_lin(p0) * sig_from_neglog2(gri + unpack_gc(p0));
        }
      }
      const float li = unpack_lin(glpk[((size_t)i << 6) | lane]);
      v = fmaxf(acc + li, 0.f);
    }
    if (LAST) psum += v;
    else xs[w * 4 + k][lane] = f2bf(v);
  }

  if (LAST) {
    pacc[w][lane] = psum;
    __syncthreads();
    if (w == 0) {
      const float t = pacc[0][lane] + pacc[1][lane] + pacc[2][lane] + pacc[3][lane];
      atomicAdd(&pool[lane], t);
    }
    return;
  }

  __syncthreads();
  // --- mm phase: wave w -> output columns nt=w ---
  const int l15 = lane & 15, kg = lane >> 4;
  const bf16x8 afrag0 = *(const bf16x8*)&xs[l15][kg * 8];
  const bf16x8 afrag1 = *(const bf16x8*)&xs[l15][32 + kg * 8];

  const float blv = bl[w * 16 + l15];
  const float bgv = bgs[w * 16 + l15];
  f32x4 accL = (f32x4){blv, blv, blv, blv};
  f32x4 accR = (f32x4){0.f, 0.f, 0.f, 0.f};
  f32x4 accC = (f32x4){bgv, bgv, bgv, bgv};

  accL = __builtin_amdgcn_mfma_f32_16x16x32_bf16(afrag0, wp[(((0 * 4 + w) * 2 + 0) << 6) + lane], accL, 0, 0, 0);
  accL = __builtin_amdgcn_mfma_f32_16x16x32_bf16(afrag1, wp[(((0 * 4 + w) * 2 + 1) << 6) + lane], accL, 0, 0, 0);
  accR = __builtin_amdgcn_mfma_f32_16x16x32_bf16(afrag0, wp[(((1 * 4 + w) * 2 + 0) << 6) + lane], accR, 0, 0, 0);
  accR = __builtin_amdgcn_mfma_f32_16x16x32_bf16(afrag1, wp[(((1 * 4 + w) * 2 + 1) << 6) + lane], accR, 0, 0, 0);
  accC = __builtin_amdgcn_mfma_f32_16x16x32_bf16(afrag0, wp[(((2 * 4 + w) * 2 + 0) << 6) + lane], accC, 0, 0, 0);
  accC = __builtin_amdgcn_mfma_f32_16x16x32_bf16(afrag1, wp[(((2 * 4 + w) * 2 + 1) << 6) + lane], accC, 0, 0, 0);

#pragma unroll
  for (int r = 0; r < 4; r++) {
    const int atom = base + kg * 4 + r;
    if (atom < N) {
      const size_t o = ((size_t)atom << 6) | (w * 16 + l15);
      gr_out[o] = f2bf(accR[r]);
      glpk_out[o] = pack_gl(accC[r], accL[r]);
    }
  }
}

// ---------- final MLP ----------
__global__ void mlp_kernel(const float* __restrict__ pool,
                           const float* __restrict__ W1,
                           const float* __restrict__ b1,
                           const float* __restrict__ W2,
                           const float* __restrict__ b2,
                           float* __restrict__ out, float invN) {
  __shared__ float p[64], h[64];
  const int tid = threadIdx.x;
  if (tid < 64) p[tid] = pool[tid] * invN;
  __syncthreads();
  if (tid < 64) {
    float s = b1[tid];
    for (int k = 0; k < 64; k++) s = fmaf(p[k], W1[k * 64 + tid], s);
    h[tid] = fmaxf(s, 0.f);
  }
  __syncthreads();
  float s = b2[tid];
  for (int k = 0; k < 64; k++) s = fmaf(h[k], W2[k * 128 + tid], s);
  out[tid] = s;
}

extern "C" void kernel_launch(void* const* d_in, const int* in_sizes, int n_in,
                              void* d_out, int out_size, void* d_ws,
                              size_t ws_size, hipStream_t stream) {
  const int*   an  = (const int*)d_in[0];
  const int*   ei  = (const int*)d_in[3];
  const float* emb = (const float*)d_in[4];
  const float* Wl  = (const float*)d_in[5];
  const float* bl  = (const float*)d_in[6];
  const float* Wg  = (const float*)d_in[7];
  const float* bg  = (const float*)d_in[8];
  const float* W1  = (const float*)d_in[9];
  const float* b1  = (const float*)d_in[10];
  const float* W2  = (const float*)d_in[11];
  const float* b2  = (const float*)d_in[12];
  float* out = (float*)d_out;

  const int N = in_sizes[0];
  const int E = in_sizes[3] / 2;
  const int* row = ei;
  const int* col = ei + E;
  const int nbuck = (N + BROWS - 1) >> BSHIFT;  // 1563 for N=100K

  const size_t NH = (size_t)N * H;
  char* ws = (char*)d_ws;
  ushort*   grA   = (ushort*)(ws);
  ushort*   grB   = (ushort*)(ws + NH * 2);
  uint32_t* glpkA = (uint32_t*)(ws + NH * 4);
  uint32_t* glpkB = (uint32_t*)(ws + NH * 4 + NH * 4);
  char* p = ws + NH * 4 + NH * 8;
  uint32_t* ebuf   = (uint32_t*)p; p += (size_t)E * 4;
  int*      cols   = (int*)p;      p += (size_t)E * 4;
  int*      offs   = (int*)p;      p += ((size_t)N + 1) * 4;
  int*      bcnt   = (int*)p;      p += 8192;
  int*      bstart = (int*)p;      p += 8196;
  int*      bcur   = (int*)p;      p += 8192;
  bf16x8*   wprep  = (bf16x8*)p;   p += 4608 * 16;
  float*    bgs    = (float*)p;    p += 192 * 4;
  float*    pool   = (float*)p;
  // total ≈ 2*12.8 + 2*25.6 + 4 + 4 + 0.4 MB + ~120KB ≈ 85.5 MB

  prep_kernel<<<18, 256, 0, stream>>>(Wl, Wg, bg, wprep, bgs);

  // --- bucket build + CSR (edges identical every layer) ---
  hipMemsetAsync(bcnt, 0, (size_t)nbuck * 4, stream);
  bucket_hist_kernel<<<1024, 256, 0, stream>>>(row, bcnt, E, nbuck);
  bucket_scan_kernel<<<1, 1024, 0, stream>>>(bcnt, bstart, bcur, offs, pool,
                                             nbuck, N, E);
  bucket_scatter_kernel<<<(E + SCHUNK - 1) / SCHUNK, 256, 0, stream>>>(
      row, col, bcur, ebuf, E, nbuck);
  csr_build_kernel<<<nbuck, 256, 0, stream>>>(ebuf, bstart, offs, cols, N);

  // layer 0 matmuls from embeddings
  node_mm0_mfma<<<(N + 63) / 64, 256, 0, stream>>>(an, emb, wprep, bl, bgs,
                                                   grA, glpkA, N);

  const int fGrid = (N + 15) / 16;
  // agg(l0) + mm(l1): A -> B
  agg_mm_kernel<false><<<fGrid, 256, 0, stream>>>(
      grA, glpkA, offs, cols, wprep + 1536, bl + H, bgs + H, grB, glpkB, pool, N);
  // agg(l1) + mm(l2): B -> A
  agg_mm_kernel<false><<<fGrid, 256, 0, stream>>>(
      grB, glpkB, offs, cols, wprep + 3072, bl + 2 * H, bgs + 2 * H, grA, glpkA,
      pool, N);
  // agg(l2) + pool
  agg_mm_kernel<true><<<fGrid, 256, 0, stream>>>(
      grA, glpkA, offs, cols, wprep, bl, bgs, grB, glpkB, pool, N);

  mlp_kernel<<<1, 128, 0, stream>>>(pool, W1, b1, W2, b2, out, 1.0f / (float)N);
}